// Round 7
// baseline (141.404 us; speedup 1.0000x reference)
//
#include <hip/hip_runtime.h>
#include <hip/hip_bf16.h>
#include <stdint.h>
#include <math.h>

#define NN 8192
#define MM 8192
#define DD 256
#define NPART ((NN / 128) * (MM / 128))  // 4096 blocks
#define LOG2E 1.44269504088896340736f
#define LN2 0.69314718055994530942f

typedef __attribute__((ext_vector_type(8))) short short8;
typedef __attribute__((ext_vector_type(4))) float float4v;
typedef __attribute__((ext_vector_type(2))) unsigned uint2v;

__device__ __forceinline__ unsigned cvt_pk_bf16(float lo, float hi) {
  unsigned r;
  asm("v_cvt_pk_bf16_f32 %0, %1, %2" : "=v"(r) : "v"(lo), "v"(hi));
  return r;
}

__global__ void convert_both(const float* __restrict__ A32,
                             const float* __restrict__ B32,
                             unsigned short* __restrict__ Abf,
                             unsigned short* __restrict__ Bbf) {
  const int n4 = NN * DD / 4;
  const int stride = gridDim.x * blockDim.x;
  for (int idx = blockIdx.x * blockDim.x + threadIdx.x; idx < 2 * n4;
       idx += stride) {
    const bool isA = idx < n4;
    const int j = isA ? idx : idx - n4;
    float4v x = isA ? ((const float4v*)A32)[j] : ((const float4v*)B32)[j];
    uint2v o;
    o[0] = cvt_pk_bf16(x[0], x[1]);
    o[1] = cvt_pk_bf16(x[2], x[3]);
    if (isA) ((uint2v*)Abf)[j] = o;
    else     ((uint2v*)Bbf)[j] = o;
  }
}

__device__ __forceinline__ short8 pack8(float4v a0, float4v a1) {
  union { short8 s; unsigned u[4]; } r;
  r.u[0] = cvt_pk_bf16(a0[0], a0[1]);
  r.u[1] = cvt_pk_bf16(a0[2], a0[3]);
  r.u[2] = cvt_pk_bf16(a1[0], a1[1]);
  r.u[3] = cvt_pk_bf16(a1[2], a1[3]);
  return r.s;
}

// L2-direct GEMM: no LDS staging, no K-loop barriers. Each lane loads its MFMA
// fragment (8 k-contiguous bf16 = 16B) straight from global; inputs (8MB bf16)
// are L2/L3-resident. 128x128 block tile, 4 waves (2x2), wave tile 64x64 via
// 4x4 mfma_f32_16x16x32_bf16, full-K unroll (8 steps of K=32).
// blockIdx remap: XCD chunk (512 blocks) + 8x8 supertile => ~1MB working set/XCD.
template <bool BF16WS>
__device__ __forceinline__ void gemm_sigloss_body(
    const unsigned short* __restrict__ Abf, const unsigned short* __restrict__ Bbf,
    const float* __restrict__ A32, const float* __restrict__ B32,
    const int* __restrict__ la, const int* __restrict__ lb,
    const float* __restrict__ scale_p, const float* __restrict__ bias_p,
    float* __restrict__ pos_part, float* __restrict__ neg_part,
    unsigned* __restrict__ cnt_part) {
  __shared__ float redp[4], redn[4];
  __shared__ unsigned redc[4];

  const int tid = threadIdx.x;
  const int w = tid >> 6;
  const int l = tid & 63;

  // XCD chunk + supertile remap (bijective over 4096 blocks)
  const int x = blockIdx.x & 7;   // XCD
  const int i = blockIdx.x >> 3;  // 0..511 within XCD chunk
  const int sgc = i >> 6;         // supertile col group 0..7
  const int j = i & 63;
  const int brow = ((x << 3) + (j >> 3)) << 7;
  const int bcol = ((sgc << 3) + (j & 7)) << 7;

  const int wrow = (w >> 1) << 6;
  const int wcol = (w & 1) << 6;
  const int col16 = l & 15;
  const int quad = l >> 4;

  float4v acc[4][4];
#pragma unroll
  for (int a = 0; a < 4; ++a)
#pragma unroll
    for (int b = 0; b < 4; ++b) acc[a][b] = (float4v){0.f, 0.f, 0.f, 0.f};

  // fragment base addresses (k-contiguous 16B per lane)
  const size_t arow = (size_t)(brow + wrow + col16);
  const size_t brow_b = (size_t)(bcol + wcol + col16);

  if constexpr (BF16WS) {
    const unsigned short* aBase = Abf + arow * DD + quad * 8;
    const unsigned short* bBase = Bbf + brow_b * DD + quad * 8;
#pragma unroll
    for (int ks = 0; ks < 8; ++ks) {  // K = 8 x 32
      short8 af[4], bfv[4];
#pragma unroll
      for (int mi = 0; mi < 4; ++mi)
        af[mi] = *(const short8*)(aBase + (size_t)mi * 16 * DD + ks * 32);
#pragma unroll
      for (int ni = 0; ni < 4; ++ni)
        bfv[ni] = *(const short8*)(bBase + (size_t)ni * 16 * DD + ks * 32);
#pragma unroll
      for (int mi = 0; mi < 4; ++mi)
#pragma unroll
        for (int ni = 0; ni < 4; ++ni)
          acc[mi][ni] = __builtin_amdgcn_mfma_f32_16x16x32_bf16(
              af[mi], bfv[ni], acc[mi][ni], 0, 0, 0);
    }
  } else {
    const float* aBase = A32 + arow * DD + quad * 8;
    const float* bBase = B32 + brow_b * DD + quad * 8;
#pragma unroll
    for (int ks = 0; ks < 8; ++ks) {
      short8 af[4], bfv[4];
#pragma unroll
      for (int mi = 0; mi < 4; ++mi) {
        const float* p = aBase + (size_t)mi * 16 * DD + ks * 32;
        af[mi] = pack8(*(const float4v*)p, *(const float4v*)(p + 4));
      }
#pragma unroll
      for (int ni = 0; ni < 4; ++ni) {
        const float* p = bBase + (size_t)ni * 16 * DD + ks * 32;
        bfv[ni] = pack8(*(const float4v*)p, *(const float4v*)(p + 4));
      }
#pragma unroll
      for (int mi = 0; mi < 4; ++mi)
#pragma unroll
        for (int ni = 0; ni < 4; ++ni)
          acc[mi][ni] = __builtin_amdgcn_mfma_f32_16x16x32_bf16(
              af[mi], bfv[ni], acc[mi][ni], 0, 0, 0);
    }
  }

  // ---- slim fused epilogue, base-2 softplus ----
  const float s2 = (*scale_p) * LOG2E;
  const float b2 = (*bias_p) * LOG2E;
  float st = 0.f, sp = 0.f;
  int pc = 0;

  int lbv[4];
#pragma unroll
  for (int ni = 0; ni < 4; ++ni) lbv[ni] = lb[bcol + wcol + (ni << 4) + col16];

#pragma unroll
  for (int mi = 0; mi < 4; ++mi) {
#pragma unroll
    for (int r = 0; r < 4; ++r) {
      const int grow = brow + wrow + (mi << 4) + (quad << 2) + r;
      const int lav = la[grow];
#pragma unroll
      for (int ni = 0; ni < 4; ++ni) {
        const float v = fmaf(s2, acc[mi][ni][r], b2);  // logit*log2e
        const bool m = (lav == lbv[ni]);
        const float u = m ? -v : v;
        const float e = __builtin_amdgcn_exp2f(-fabsf(u));
        const float xx = fmaxf(u, 0.f) + __builtin_amdgcn_logf(1.f + e);
        st += xx;
        if (__builtin_expect(__any(m), 0)) {
          if (m) { sp += xx; ++pc; }
        }
      }
    }
  }

  // deterministic per-block partials
#pragma unroll
  for (int off = 32; off > 0; off >>= 1) {
    st += __shfl_down(st, off);
    sp += __shfl_down(sp, off);
    pc += __shfl_down(pc, off);
  }
  if (l == 0) { redp[w] = sp; redn[w] = st; redc[w] = (unsigned)pc; }
  __syncthreads();
  if (tid == 0) {
    const float tp = redp[0] + redp[1] + redp[2] + redp[3];
    const float tt = redn[0] + redn[1] + redn[2] + redn[3];
    pos_part[blockIdx.x] = LN2 * tp;
    neg_part[blockIdx.x] = LN2 * (tt - tp);
    cnt_part[blockIdx.x] = redc[0] + redc[1] + redc[2] + redc[3];
  }
}

__global__ __launch_bounds__(256, 4) void gemm_sigloss_bf16ws(
    const unsigned short* __restrict__ Abf, const unsigned short* __restrict__ Bbf,
    const int* __restrict__ la, const int* __restrict__ lb,
    const float* __restrict__ scale_p, const float* __restrict__ bias_p,
    float* __restrict__ pos_part, float* __restrict__ neg_part,
    unsigned* __restrict__ cnt_part) {
  gemm_sigloss_body<true>(Abf, Bbf, nullptr, nullptr, la, lb, scale_p, bias_p,
                          pos_part, neg_part, cnt_part);
}

__global__ __launch_bounds__(256, 2) void gemm_sigloss_f32(
    const float* __restrict__ A32, const float* __restrict__ B32,
    const int* __restrict__ la, const int* __restrict__ lb,
    const float* __restrict__ scale_p, const float* __restrict__ bias_p,
    float* __restrict__ pos_part, float* __restrict__ neg_part,
    unsigned* __restrict__ cnt_part) {
  gemm_sigloss_body<false>(nullptr, nullptr, A32, B32, la, lb, scale_p, bias_p,
                           pos_part, neg_part, cnt_part);
}

__global__ __launch_bounds__(256) void finalize_loss(
    const float* __restrict__ pos_part, const float* __restrict__ neg_part,
    const unsigned* __restrict__ cnt_part, float* __restrict__ out) {
  __shared__ float rp[4], rn[4];
  __shared__ unsigned rc[4];
  const int w = threadIdx.x >> 6;
  const int l = threadIdx.x & 63;
  float ps = 0.f, ns = 0.f;
  int pc = 0;
  for (int i = threadIdx.x; i < NPART; i += 256) {
    ps += pos_part[i];
    ns += neg_part[i];
    pc += (int)cnt_part[i];
  }
#pragma unroll
  for (int off = 32; off > 0; off >>= 1) {
    ps += __shfl_down(ps, off);
    ns += __shfl_down(ns, off);
    pc += __shfl_down(pc, off);
  }
  if (l == 0) { rp[w] = ps; rn[w] = ns; rc[w] = (unsigned)pc; }
  __syncthreads();
  if (threadIdx.x == 0) {
    double tp = (double)rp[0] + rp[1] + rp[2] + rp[3];
    double tn = (double)rn[0] + rn[1] + rn[2] + rn[3];
    long long tc = (long long)rc[0] + rc[1] + rc[2] + rc[3];
    double num_pos = (double)(tc > 1 ? tc : 1);
    long long negc = (long long)NN * MM - tc;
    double num_neg = (double)(negc > 1 ? negc : 1);
    out[0] = (float)(tp / num_pos + tn / num_neg * (double)(NN - 1));
  }
}

extern "C" void kernel_launch(void* const* d_in, const int* in_sizes, int n_in,
                              void* d_out, int out_size, void* d_ws, size_t ws_size,
                              hipStream_t stream) {
  const float* A32 = (const float*)d_in[0];
  const float* B32 = (const float*)d_in[1];
  const int* la = (const int*)d_in[2];
  const int* lb = (const int*)d_in[3];
  const float* scale_p = (const float*)d_in[4];
  const float* bias_p = (const float*)d_in[5];
  float* out = (float*)d_out;

  char* ws = (char*)d_ws;
  float* pos_part = (float*)ws;                       // 4096 f32
  float* neg_part = pos_part + NPART;                 // 4096 f32
  unsigned* cnt_part = (unsigned*)(neg_part + NPART); // 4096 u32
  unsigned short* Abf = (unsigned short*)(ws + 65536);
  unsigned short* Bbf = Abf + (size_t)NN * DD;

  const size_t need = 65536 + 2ull * (size_t)NN * DD * 2;
  const bool usebf = (ws_size >= need);

  if (usebf) {
    convert_both<<<2048, 256, 0, stream>>>(A32, B32, Abf, Bbf);
    gemm_sigloss_bf16ws<<<NPART, 256, 0, stream>>>(Abf, Bbf, la, lb, scale_p,
                                                   bias_p, pos_part, neg_part,
                                                   cnt_part);
  } else {
    gemm_sigloss_f32<<<NPART, 256, 0, stream>>>(A32, B32, la, lb, scale_p,
                                                bias_p, pos_part, neg_part,
                                                cnt_part);
  }
  finalize_loss<<<1, 256, 0, stream>>>(pos_part, neg_part, cnt_part, out);
}

// Round 8
// 53.099 us; speedup vs baseline: 2.6631x; 2.6631x over previous
//
#include <hip/hip_runtime.h>
#include <hip/hip_bf16.h>
#include <stdint.h>
#include <math.h>

#define NN 8192
#define MM 8192
#define DD 256
#define NPART ((NN / 128) * (MM / 128))  // 4096 blocks
#define LOG2E 1.44269504088896340736f
#define LN2 0.69314718055994530942f

typedef __attribute__((ext_vector_type(8))) short short8;
typedef __attribute__((ext_vector_type(4))) float float4v;
typedef __attribute__((ext_vector_type(2))) unsigned uint2v;

__device__ __forceinline__ unsigned cvt_pk_bf16(float lo, float hi) {
  unsigned r;
  asm("v_cvt_pk_bf16_f32 %0, %1, %2" : "=v"(r) : "v"(lo), "v"(hi));
  return r;
}

// f32 -> fp8 e4m3 (OCP), 8 elements per iteration per thread
__global__ void convert_both_fp8(const float* __restrict__ A32,
                                 const float* __restrict__ B32,
                                 unsigned char* __restrict__ A8,
                                 unsigned char* __restrict__ B8) {
  const int n8 = NN * DD / 8;  // per array
  const int stride = gridDim.x * blockDim.x;
  for (int idx = blockIdx.x * blockDim.x + threadIdx.x; idx < 2 * n8;
       idx += stride) {
    const bool isA = idx < n8;
    const int j = isA ? idx : idx - n8;
    const float4v* src = (const float4v*)(isA ? A32 : B32);
    const float4v x0 = src[2 * j];
    const float4v x1 = src[2 * j + 1];
    int lo = __builtin_amdgcn_cvt_pk_fp8_f32(x0[0], x0[1], 0, false);
    lo = __builtin_amdgcn_cvt_pk_fp8_f32(x0[2], x0[3], lo, true);
    int hi = __builtin_amdgcn_cvt_pk_fp8_f32(x1[0], x1[1], 0, false);
    hi = __builtin_amdgcn_cvt_pk_fp8_f32(x1[2], x1[3], hi, true);
    uint2v o;
    o[0] = (unsigned)lo;
    o[1] = (unsigned)hi;
    ((uint2v*)(isA ? A8 : B8))[j] = o;
  }
}

__device__ __forceinline__ short8 pack8(float4v a0, float4v a1) {
  union { short8 s; unsigned u[4]; } r;
  r.u[0] = cvt_pk_bf16(a0[0], a0[1]);
  r.u[1] = cvt_pk_bf16(a0[2], a0[3]);
  r.u[2] = cvt_pk_bf16(a1[0], a1[1]);
  r.u[3] = cvt_pk_bf16(a1[2], a1[3]);
  return r.s;
}

// ======================= fp8 GEMM + fused loss =======================
// 128x128 tile, BK=64, 4 waves (2x2), wave 64x64 via 4x4 mfma_f32_16x16x32_fp8_fp8.
// LDS: [128 rows][64 k] fp8 = 8KB per operand, single-buffered (16KB total) ->
// high blocks/CU for TLP (round-6 lesson). Rows 64B; swizzle at 16B pieces:
// phys_piece = piece ^ ((row>>1)&3)  (2-way max on ds_read_b64 = free, m136).
// Staged via pre-swizzled GLOBAL source + linear LDS dest (global_load_lds w=16).
__global__ __launch_bounds__(256, 4) void gemm_sigloss_fp8ws(
    const unsigned char* __restrict__ A8, const unsigned char* __restrict__ B8,
    const int* __restrict__ la, const int* __restrict__ lb,
    const float* __restrict__ scale_p, const float* __restrict__ bias_p,
    float* __restrict__ pos_part, float* __restrict__ neg_part,
    unsigned* __restrict__ cnt_part) {
  __shared__ unsigned char As[128 * 64];
  __shared__ unsigned char Bs[128 * 64];
  __shared__ float redp[4], redn[4];
  __shared__ unsigned redc[4];

  const int tid = threadIdx.x;
  const int w = tid >> 6;
  const int l = tid & 63;
  // bijective XCD swizzle: 4096 % 8 == 0
  const int bid = ((blockIdx.x & 7) << 9) + (blockIdx.x >> 3);
  const int brow = (bid >> 6) << 7;
  const int bcol = (bid & 63) << 7;
  const int wrow = (w >> 1) << 6;
  const int wcol = (w & 1) << 6;
  const int col16 = l & 15;
  const int quad = l >> 4;

  float4v acc[4][4];
#pragma unroll
  for (int a = 0; a < 4; ++a)
#pragma unroll
    for (int b = 0; b < 4; ++b) acc[a][b] = (float4v){0.f, 0.f, 0.f, 0.f};

  // staging: 256 threads x 16B = 4KB = 64 rows per issue; 2 issues per operand.
  // thread t -> row (t>>2), piece (t&3); source piece pre-swizzled.
  const int srow = tid >> 2;                       // row within 64-row group
  const int spiece = (tid & 3) ^ ((tid >> 3) & 3); // src piece (involution)
  const int ssrc = spiece << 4;                    // byte offset within row K-tile

  // ds_read swizzle constants
  const int rsw = (col16 >> 1) & 3;

  for (int kt = 0; kt < 4; ++kt) {
    const int k0 = kt << 6;
#pragma unroll
    for (int i = 0; i < 2; ++i) {
      const int r = (i << 6) + srow;
      __builtin_amdgcn_global_load_lds(
          (const __attribute__((address_space(1))) void*)(
              A8 + (size_t)(brow + r) * DD + k0 + ssrc),
          (__attribute__((address_space(3))) void*)(&As[(i << 12) + tid * 16]),
          16, 0, 0);
      __builtin_amdgcn_global_load_lds(
          (const __attribute__((address_space(1))) void*)(
              B8 + (size_t)(bcol + r) * DD + k0 + ssrc),
          (__attribute__((address_space(3))) void*)(&Bs[(i << 12) + tid * 16]),
          16, 0, 0);
    }
    __syncthreads();
#pragma unroll
    for (int kk = 0; kk < 2; ++kk) {
      // logical piece = kk*2 + (quad>>1); half = quad&1
      const int lp = (kk << 1) + (quad >> 1);
      const int off = ((lp ^ rsw) << 4) + ((quad & 1) << 3);
      long af[4], bfv[4];
#pragma unroll
      for (int mi = 0; mi < 4; ++mi) {
        const int row = wrow + (mi << 4) + col16;
        af[mi] = *(const long*)(&As[row * 64 + off]);
      }
#pragma unroll
      for (int ni = 0; ni < 4; ++ni) {
        const int row = wcol + (ni << 4) + col16;
        bfv[ni] = *(const long*)(&Bs[row * 64 + off]);
      }
#pragma unroll
      for (int mi = 0; mi < 4; ++mi)
#pragma unroll
        for (int ni = 0; ni < 4; ++ni)
          acc[mi][ni] = __builtin_amdgcn_mfma_f32_16x16x32_fp8_fp8(
              af[mi], bfv[ni], acc[mi][ni], 0, 0, 0);
    }
    __syncthreads();
  }

  // ---- slim fused epilogue, base-2 softplus ----
  const float s2 = (*scale_p) * LOG2E;
  const float b2 = (*bias_p) * LOG2E;
  float st = 0.f, sp = 0.f;
  int pc = 0;

  int lbv[4];
#pragma unroll
  for (int ni = 0; ni < 4; ++ni) lbv[ni] = lb[bcol + wcol + (ni << 4) + col16];

#pragma unroll
  for (int mi = 0; mi < 4; ++mi) {
#pragma unroll
    for (int r = 0; r < 4; ++r) {
      const int grow = brow + wrow + (mi << 4) + (quad << 2) + r;
      const int lav = la[grow];
#pragma unroll
      for (int ni = 0; ni < 4; ++ni) {
        const float v = fmaf(s2, acc[mi][ni][r], b2);
        const bool m = (lav == lbv[ni]);
        const float u = m ? -v : v;
        const float e = __builtin_amdgcn_exp2f(-fabsf(u));
        const float xx = fmaxf(u, 0.f) + __builtin_amdgcn_logf(1.f + e);
        st += xx;
        if (__builtin_expect(__any(m), 0)) {
          if (m) { sp += xx; ++pc; }
        }
      }
    }
  }

#pragma unroll
  for (int off = 32; off > 0; off >>= 1) {
    st += __shfl_down(st, off);
    sp += __shfl_down(sp, off);
    pc += __shfl_down(pc, off);
  }
  if (l == 0) { redp[w] = sp; redn[w] = st; redc[w] = (unsigned)pc; }
  __syncthreads();
  if (tid == 0) {
    const float tp = redp[0] + redp[1] + redp[2] + redp[3];
    const float tt = redn[0] + redn[1] + redn[2] + redn[3];
    pos_part[blockIdx.x] = LN2 * tp;
    neg_part[blockIdx.x] = LN2 * (tt - tp);
    cnt_part[blockIdx.x] = redc[0] + redc[1] + redc[2] + redc[3];
  }
}

// ============== f32 fallback: round-6 bf16-in-LDS structure ==============
__global__ __launch_bounds__(256, 3) void gemm_sigloss_f32(
    const float* __restrict__ A32, const float* __restrict__ B32,
    const int* __restrict__ la, const int* __restrict__ lb,
    const float* __restrict__ scale_p, const float* __restrict__ bias_p,
    float* __restrict__ pos_part, float* __restrict__ neg_part,
    unsigned* __restrict__ cnt_part) {
  __shared__ unsigned short As[128 * 64];
  __shared__ unsigned short Bs[128 * 64];
  __shared__ float redp[4], redn[4];
  __shared__ unsigned redc[4];

  const int tid = threadIdx.x;
  const int w = tid >> 6;
  const int l = tid & 63;
  const int bid = ((blockIdx.x & 7) << 9) + (blockIdx.x >> 3);
  const int brow = (bid >> 6) << 7;
  const int bcol = (bid & 63) << 7;
  const int wrow = (w >> 1) << 6;
  const int wcol = (w & 1) << 6;
  const int col16 = l & 15;
  const int quad = l >> 4;

  float4v acc[4][4];
#pragma unroll
  for (int a = 0; a < 4; ++a)
#pragma unroll
    for (int b = 0; b < 4; ++b) acc[a][b] = (float4v){0.f, 0.f, 0.f, 0.f};

  const int rg = l >> 3;
  const int c8 = l & 7;
  const int ksw = (c8 ^ rg) << 3;

  for (int kt = 0; kt < DD / 64; ++kt) {
    const int k0 = kt << 6;
#pragma unroll
    for (int i = 0; i < 4; ++i) {
      const int trow = (w << 5) + (i << 3) + rg;
      const float4v* pa = (const float4v*)(A32 + (size_t)(brow + trow) * DD + k0 + ksw);
      const float4v* pb = (const float4v*)(B32 + (size_t)(bcol + trow) * DD + k0 + ksw);
      const int lofs = ((w << 2) + i) << 9;
      *(short8*)((char*)As + (size_t)lofs * 2 + (size_t)l * 16) = pack8(pa[0], pa[1]);
      *(short8*)((char*)Bs + (size_t)lofs * 2 + (size_t)l * 16) = pack8(pb[0], pb[1]);
    }
    __syncthreads();
#pragma unroll
    for (int kk = 0; kk < 2; ++kk) {
      const int kb = (kk << 6) + (quad << 4);
      const int sw = (col16 & 7) << 4;
      short8 af[4], bfv[4];
#pragma unroll
      for (int mi = 0; mi < 4; ++mi) {
        const int row = wrow + (mi << 4) + col16;
        af[mi] = *(const short8*)((const char*)As + row * 128 + (kb ^ sw));
      }
#pragma unroll
      for (int ni = 0; ni < 4; ++ni) {
        const int row = wcol + (ni << 4) + col16;
        bfv[ni] = *(const short8*)((const char*)Bs + row * 128 + (kb ^ sw));
      }
#pragma unroll
      for (int mi = 0; mi < 4; ++mi)
#pragma unroll
        for (int ni = 0; ni < 4; ++ni)
          acc[mi][ni] = __builtin_amdgcn_mfma_f32_16x16x32_bf16(
              af[mi], bfv[ni], acc[mi][ni], 0, 0, 0);
    }
    __syncthreads();
  }

  const float s2 = (*scale_p) * LOG2E;
  const float b2 = (*bias_p) * LOG2E;
  float st = 0.f, sp = 0.f;
  int pc = 0;
  int lbv[4];
#pragma unroll
  for (int ni = 0; ni < 4; ++ni) lbv[ni] = lb[bcol + wcol + (ni << 4) + col16];
#pragma unroll
  for (int mi = 0; mi < 4; ++mi) {
#pragma unroll
    for (int r = 0; r < 4; ++r) {
      const int grow = brow + wrow + (mi << 4) + (quad << 2) + r;
      const int lav = la[grow];
#pragma unroll
      for (int ni = 0; ni < 4; ++ni) {
        const float v = fmaf(s2, acc[mi][ni][r], b2);
        const bool m = (lav == lbv[ni]);
        const float u = m ? -v : v;
        const float e = __builtin_amdgcn_exp2f(-fabsf(u));
        const float xx = fmaxf(u, 0.f) + __builtin_amdgcn_logf(1.f + e);
        st += xx;
        if (__builtin_expect(__any(m), 0)) {
          if (m) { sp += xx; ++pc; }
        }
      }
    }
  }
#pragma unroll
  for (int off = 32; off > 0; off >>= 1) {
    st += __shfl_down(st, off);
    sp += __shfl_down(sp, off);
    pc += __shfl_down(pc, off);
  }
  if (l == 0) { redp[w] = sp; redn[w] = st; redc[w] = (unsigned)pc; }
  __syncthreads();
  if (tid == 0) {
    const float tp = redp[0] + redp[1] + redp[2] + redp[3];
    const float tt = redn[0] + redn[1] + redn[2] + redn[3];
    pos_part[bid] = LN2 * tp;
    neg_part[bid] = LN2 * (tt - tp);
    cnt_part[bid] = redc[0] + redc[1] + redc[2] + redc[3];
  }
}

__global__ __launch_bounds__(256) void finalize_loss(
    const float* __restrict__ pos_part, const float* __restrict__ neg_part,
    const unsigned* __restrict__ cnt_part, float* __restrict__ out) {
  __shared__ float rp[4], rn[4];
  __shared__ unsigned rc[4];
  const int w = threadIdx.x >> 6;
  const int l = threadIdx.x & 63;
  float ps = 0.f, ns = 0.f;
  int pc = 0;
  for (int i = threadIdx.x; i < NPART; i += 256) {
    ps += pos_part[i];
    ns += neg_part[i];
    pc += (int)cnt_part[i];
  }
#pragma unroll
  for (int off = 32; off > 0; off >>= 1) {
    ps += __shfl_down(ps, off);
    ns += __shfl_down(ns, off);
    pc += __shfl_down(pc, off);
  }
  if (l == 0) { rp[w] = ps; rn[w] = ns; rc[w] = (unsigned)pc; }
  __syncthreads();
  if (threadIdx.x == 0) {
    double tp = (double)rp[0] + rp[1] + rp[2] + rp[3];
    double tn = (double)rn[0] + rn[1] + rn[2] + rn[3];
    long long tc = (long long)rc[0] + rc[1] + rc[2] + rc[3];
    double num_pos = (double)(tc > 1 ? tc : 1);
    long long negc = (long long)NN * MM - tc;
    double num_neg = (double)(negc > 1 ? negc : 1);
    out[0] = (float)(tp / num_pos + tn / num_neg * (double)(NN - 1));
  }
}

extern "C" void kernel_launch(void* const* d_in, const int* in_sizes, int n_in,
                              void* d_out, int out_size, void* d_ws, size_t ws_size,
                              hipStream_t stream) {
  const float* A32 = (const float*)d_in[0];
  const float* B32 = (const float*)d_in[1];
  const int* la = (const int*)d_in[2];
  const int* lb = (const int*)d_in[3];
  const float* scale_p = (const float*)d_in[4];
  const float* bias_p = (const float*)d_in[5];
  float* out = (float*)d_out;

  char* ws = (char*)d_ws;
  float* pos_part = (float*)ws;                       // 4096 f32
  float* neg_part = pos_part + NPART;                 // 4096 f32
  unsigned* cnt_part = (unsigned*)(neg_part + NPART); // 4096 u32
  unsigned char* A8 = (unsigned char*)(ws + 65536);
  unsigned char* B8 = A8 + (size_t)NN * DD;

  const size_t need = 65536 + 2ull * (size_t)NN * DD;
  const bool use8 = (ws_size >= need);

  if (use8) {
    convert_both_fp8<<<1024, 256, 0, stream>>>(A32, B32, A8, B8);
    gemm_sigloss_fp8ws<<<NPART, 256, 0, stream>>>(A8, B8, la, lb, scale_p,
                                                  bias_p, pos_part, neg_part,
                                                  cnt_part);
  } else {
    gemm_sigloss_f32<<<NPART, 256, 0, stream>>>(A32, B32, la, lb, scale_p,
                                                bias_p, pos_part, neg_part,
                                                cnt_part);
  }
  finalize_loss<<<1, 256, 0, stream>>>(pos_part, neg_part, cnt_part, out);
}